// Round 4
// baseline (138.112 us; speedup 1.0000x reference)
//
#include <hip/hip_runtime.h>

#define NCLS 256
#define NDF  512
#define BSZ  1024
#define ALP  0.1f
#define LSTR 68   // LDS row stride in floats: 68*4=272 ≡ 0 (mod 16) -> aligned b128 frag reads
#define NBLK 512  // grid size == barrier target; co-residency: 29.7KB LDS -> 5 blk/CU -> cap 1280

// score[b,c] = s1[b,c]-s1[b,t] + 0.5*ALP*(R[t,c]-R[t,t]),  t=gt[b]
//   s1 = df @ fc^T                       (1024x256x512, splitK=4)
//   R[t,c] = sum_d (fc[c,d]^2 - 2 fc[c,d] fc[t,d]) var[t,d]   (256x256, 8 dim-chunks)
// var: faithful per-class sequential recurrence, computed redundantly per R block.
// Single dispatch: phase1 (partials) -> device-scope grid barrier -> phase2 (fold+output).

__device__ __forceinline__ void gemm_inner(const float (*As)[LSTR], const float (*Bs)[LSTR],
                                           int tx, int ty, float4* acc) {
#pragma unroll
    for (int kk = 0; kk < 32; ++kk) {
        const float4 a = *(const float4*)&As[kk][ty * 4];
        const float4 b = *(const float4*)&Bs[kk][tx * 4];
        acc[0].x += a.x * b.x; acc[0].y += a.x * b.y; acc[0].z += a.x * b.z; acc[0].w += a.x * b.w;
        acc[1].x += a.y * b.x; acc[1].y += a.y * b.y; acc[1].z += a.y * b.z; acc[1].w += a.y * b.w;
        acc[2].x += a.z * b.x; acc[2].y += a.z * b.y; acc[2].z += a.z * b.z; acc[2].w += a.z * b.w;
        acc[3].x += a.w * b.x; acc[3].y += a.w * b.y; acc[3].z += a.w * b.z; acc[3].w += a.w * b.w;
    }
}

// grid: NBLK blocks x 256 threads.
//  bid <  256      : s1 partial. z=bid&3 (K chunk of 128), tile=bid>>2: bm=tile&15, bn=tile>>4.
//  256 <= bid < 384: R partial.  r=bid-256; z=r&7 (dim chunk of 64), tile=r>>3: bm=tile&3, bn=tile>>2.
//  bid >= 384      : no phase-1 work (barrier + phase-2 only).
__global__ __launch_bounds__(256) void fused_all(const float* __restrict__ df,
                                                 const int* __restrict__ gt,
                                                 const float* __restrict__ fc,
                                                 float* __restrict__ s1p,
                                                 float* __restrict__ Rp,
                                                 unsigned int* __restrict__ bar,
                                                 float* __restrict__ out) {
    __shared__ float As[32][LSTR];
    __shared__ float Bs[32][LSTR];
    __shared__ int gts[BSZ];
    __shared__ unsigned long long bmap[64 * 16];

    const int tid = threadIdx.x;
    const int bid = blockIdx.x;
    const int tx = tid & 15, ty = tid >> 4;

    float4 acc[4];
    acc[0] = make_float4(0.f, 0.f, 0.f, 0.f);
    acc[1] = acc[0]; acc[2] = acc[0]; acc[3] = acc[0];

    if (bid < 256) {
        // ------------------------------- s1 path -------------------------------
        const int z = bid & 3;
        const int tile = bid >> 2;
        const int bm = tile & 15, bn = tile >> 4;
        const int arow = tid >> 2;              // 0..63
        const int kq = (tid & 3) << 3;          // 0,8,16,24
        const float* Ag = df + (bm * 64 + arow) * NDF + z * 128 + kq;
        const float* Bg = fc + (bn * 64 + arow) * NDF + z * 128 + kq;

        float4 a0 = *(const float4*)Ag, a1 = *(const float4*)(Ag + 4);
        float4 b0 = *(const float4*)Bg, b1 = *(const float4*)(Bg + 4);
#pragma unroll 1
        for (int ks = 0; ks < 4; ++ks) {
            __syncthreads();
            As[kq + 0][arow] = a0.x; As[kq + 1][arow] = a0.y; As[kq + 2][arow] = a0.z; As[kq + 3][arow] = a0.w;
            As[kq + 4][arow] = a1.x; As[kq + 5][arow] = a1.y; As[kq + 6][arow] = a1.z; As[kq + 7][arow] = a1.w;
            Bs[kq + 0][arow] = b0.x; Bs[kq + 1][arow] = b0.y; Bs[kq + 2][arow] = b0.z; Bs[kq + 3][arow] = b0.w;
            Bs[kq + 4][arow] = b1.x; Bs[kq + 5][arow] = b1.y; Bs[kq + 6][arow] = b1.z; Bs[kq + 7][arow] = b1.w;
            __syncthreads();
            if (ks < 3) {
                const int off = (ks + 1) * 32;
                a0 = *(const float4*)(Ag + off); a1 = *(const float4*)(Ag + off + 4);
                b0 = *(const float4*)(Bg + off); b1 = *(const float4*)(Bg + off + 4);
            }
            gemm_inner(As, Bs, tx, ty, acc);
        }
        float* Cp = s1p + z * (BSZ * NCLS) + (bm * 64 + ty * 4) * NCLS + bn * 64 + tx * 4;
#pragma unroll
        for (int i = 0; i < 4; ++i) *(float4*)(Cp + i * NCLS) = acc[i];
    } else if (bid < 384) {
        // ------------------------------- R path --------------------------------
        const int r = bid - 256;
        const int z = r & 7;                    // dim chunk
        const int tile = r >> 3;
        const int bm = tile & 3, bn = tile >> 2;
        const int D0 = z * 64;
        const int clocal = tid >> 2;            // 0..63: class within tile
        const int dg = tid & 3;                 // 0..3: 16-dim group
        const int myclass = bm * 64 + clocal;
        const int dim0 = D0 + dg * 16;

        for (int i = tid; i < BSZ; i += 256) gts[i] = gt[i];
        for (int i = tid; i < 1024; i += 256) bmap[i] = 0ull;
        __syncthreads();
        // order-preserving per-class sample bitmap (64 classes x 1024 bits)
        for (int i = tid; i < BSZ; i += 256) {
            const int c = gts[i] - bm * 64;
            if ((unsigned)c < 64u) atomicOr(&bmap[c * 16 + (i >> 6)], 1ull << (i & 63));
        }
        const float* fct = fc + myclass * NDF + dim0;
        float fcq[16];
        {
            const float4 q0 = ((const float4*)fct)[0], q1 = ((const float4*)fct)[1];
            const float4 q2 = ((const float4*)fct)[2], q3 = ((const float4*)fct)[3];
            fcq[0]=q0.x; fcq[1]=q0.y; fcq[2]=q0.z; fcq[3]=q0.w;
            fcq[4]=q1.x; fcq[5]=q1.y; fcq[6]=q1.z; fcq[7]=q1.w;
            fcq[8]=q2.x; fcq[9]=q2.y; fcq[10]=q2.z; fcq[11]=q2.w;
            fcq[12]=q3.x; fcq[13]=q3.y; fcq[14]=q3.z; fcq[15]=q3.w;
        }
        __syncthreads();

        // sequential running-var recurrence for (myclass, dims dim0..dim0+16)
        float m[16], v[16];
#pragma unroll
        for (int j = 0; j < 16; ++j) { m[j] = 0.f; v[j] = 0.f; }
        float nf = 0.f;
        {
            int w = 0;
            unsigned long long bits = bmap[clocal * 16];
            auto next = [&]() -> int {
                while (bits == 0ull) {
                    if (w >= 15) return -1;
                    bits = bmap[clocal * 16 + (++w)];
                }
                const int b = __ffsll((unsigned long long)bits) - 1;
                bits &= bits - 1ull;
                return (w << 6) + b;
            };
            int cur = next();
            float f[16];
            if (cur >= 0) {
                const float* p = df + cur * NDF + dim0;
                const float4 q0 = ((const float4*)p)[0], q1 = ((const float4*)p)[1];
                const float4 q2 = ((const float4*)p)[2], q3 = ((const float4*)p)[3];
                f[0]=q0.x; f[1]=q0.y; f[2]=q0.z; f[3]=q0.w;
                f[4]=q1.x; f[5]=q1.y; f[6]=q1.z; f[7]=q1.w;
                f[8]=q2.x; f[9]=q2.y; f[10]=q2.z; f[11]=q2.w;
                f[12]=q3.x; f[13]=q3.y; f[14]=q3.z; f[15]=q3.w;
            }
            while (cur >= 0) {
                const int nxt = next();
                float g[16];
                if (nxt >= 0) {   // prefetch next sample before the dependent update
                    const float* p = df + nxt * NDF + dim0;
                    const float4 q0 = ((const float4*)p)[0], q1 = ((const float4*)p)[1];
                    const float4 q2 = ((const float4*)p)[2], q3 = ((const float4*)p)[3];
                    g[0]=q0.x; g[1]=q0.y; g[2]=q0.z; g[3]=q0.w;
                    g[4]=q1.x; g[5]=q1.y; g[6]=q1.z; g[7]=q1.w;
                    g[8]=q2.x; g[9]=q2.y; g[10]=q2.z; g[11]=q2.w;
                    g[12]=q3.x; g[13]=q3.y; g[14]=q3.z; g[15]=q3.w;
                }
                const float c2 = 1.0f / (nf + 1.0f);
                const float c1 = nf * c2;
                const float c12 = c1 * c2;
#pragma unroll
                for (int j = 0; j < 16; ++j) {
                    m[j] = m[j] * c1 + f[j] * c2;     // == f when nf==0
                    const float a = f[j] - m[j];
                    v[j] = v[j] * c1 + a * a * c12;
                }
                nf += 1.0f;
#pragma unroll
                for (int j = 0; j < 16; ++j) f[j] = g[j];
                cur = nxt;
            }
        }

        // GEMM: 4 k-steps over the 64-dim chunk (2 linear + 2 quadratic)
        const int crow = tid >> 2, kq = (tid & 3) << 3;
        const float* Bg = fc + (bn * 64 + crow) * NDF + D0;
        float4 b0 = *(const float4*)(Bg + kq), b1 = *(const float4*)(Bg + kq + 4);
#pragma unroll 1
        for (int ks = 0; ks < 4; ++ks) {
            const bool quad = (ks >= 2);
            float4 w0 = b0, w1 = b1;
            if (quad) {
                w0.x *= w0.x; w0.y *= w0.y; w0.z *= w0.z; w0.w *= w0.w;
                w1.x *= w1.x; w1.y *= w1.y; w1.z *= w1.z; w1.w *= w1.w;
            }
            __syncthreads();
            if ((dg >> 1) == (ks & 1)) {   // this thread's dims fall in this k-step
                const int kb = (dg & 1) * 16;
#pragma unroll
                for (int j = 0; j < 16; ++j) {
                    As[kb + j][clocal] = quad ? v[j] : (-2.f * fcq[j] * v[j]);
                }
            }
            Bs[kq + 0][crow] = w0.x; Bs[kq + 1][crow] = w0.y; Bs[kq + 2][crow] = w0.z; Bs[kq + 3][crow] = w0.w;
            Bs[kq + 4][crow] = w1.x; Bs[kq + 5][crow] = w1.y; Bs[kq + 6][crow] = w1.z; Bs[kq + 7][crow] = w1.w;
            __syncthreads();
            if (ks < 3) {   // prefetch next step's B columns (alternate 32-dim halves)
                const int off = ((ks + 1) & 1) * 32;
                b0 = *(const float4*)(Bg + off + kq);
                b1 = *(const float4*)(Bg + off + kq + 4);
            }
            gemm_inner(As, Bs, tx, ty, acc);
        }
        float* Cp = Rp + z * (NCLS * NCLS) + (bm * 64 + ty * 4) * NCLS + bn * 64 + tx * 4;
#pragma unroll
        for (int i = 0; i < 4; ++i) *(float4*)(Cp + i * NCLS) = acc[i];
    }
    // else: barrier-helper block, goes straight to the barrier.

    // ----------------------- device-scope grid barrier ------------------------
    // Release: every thread fences its partial-sum stores (agent scope: L1 flush
    // + L2 writeback to coherence point), block syncs, one arrival per block.
    __threadfence();
    __syncthreads();
    if (tid == 0) {
        atomicAdd(bar, 1u);
        while (atomicAdd(bar, 0u) < (unsigned)NBLK) __builtin_amdgcn_s_sleep(2);
    }
    __syncthreads();
    __threadfence();   // acquire: invalidate stale L1/L2 lines before reading partials

    // ------------------------------- phase 2 ----------------------------------
    // out[b,c] = (v1[b,c]-v1[b,t]) + 0.5*ALP*(vR[t,c]-vR[t,t]); 2 rows per block.
    const int c = tid;
#pragma unroll 1
    for (int b = bid; b < BSZ; b += NBLK) {
        const int t = gt[b];   // block-uniform broadcast load
        float v1 = 0.f, v1t = 0.f;
#pragma unroll
        for (int zz = 0; zz < 4; ++zz) {
            const float* row = s1p + zz * (BSZ * NCLS) + b * NCLS;
            v1 += row[c];
            v1t += row[t];     // same-address broadcast across the wave
        }
        float vR = 0.f, vRt = 0.f;
#pragma unroll
        for (int zz = 0; zz < 8; ++zz) {
            const float* row = Rp + zz * (NCLS * NCLS) + t * NCLS;
            vR += row[c];
            vRt += row[t];
        }
        out[b * NCLS + c] = (v1 - v1t) + 0.5f * ALP * (vR - vRt);
    }
}

// ---------------------------------------------------------------------------
extern "C" void kernel_launch(void* const* d_in, const int* in_sizes, int n_in,
                              void* d_out, int out_size, void* d_ws, size_t ws_size,
                              hipStream_t stream) {
    const float* df = (const float*)d_in[0];
    const int* gt = (const int*)d_in[1];
    const float* fc = (const float*)d_in[2];
    float* out = (float*)d_out;

    float* ws = (float*)d_ws;
    float* s1p = ws;                           // 4*BSZ*NCLS  = 1,048,576 f (4 MB)
    float* Rp = s1p + 4 * BSZ * NCLS;          // 8*NCLS*NCLS =   524,288 f (2 MB)
    unsigned int* bar = (unsigned int*)(Rp + 8 * NCLS * NCLS);

    hipMemsetAsync(bar, 0, sizeof(unsigned int), stream);  // reset barrier each call
    fused_all<<<NBLK, 256, 0, stream>>>(df, gt, fc, s1p, Rp, bar, out);
}

// Round 5
// 61.321 us; speedup vs baseline: 2.2523x; 2.2523x over previous
//
#include <hip/hip_runtime.h>

#define NCLS 256
#define NDF  512
#define BSZ  1024
#define ALP  0.1f
#define LSTR 68   // LDS row stride in floats: 68*4=272 ≡ 0 (mod 16) -> aligned b128 frag reads
#define NBLK 512  // grid == barrier target; 29.7KB LDS, 88 VGPR -> 5 blk/CU -> capacity 1280 >= 512

// score[b,c] = s1[b,c]-s1[b,t] + 0.5*ALP*(R[t,c]-R[t,t]),  t=gt[b]
//   s1 = df @ fc^T                       (1024x256x512, splitK=4)
//   R[t,c] = sum_d (fc[c,d]^2 - 2 fc[c,d] fc[t,d]) var[t,d]   (256x256, 8 dim-chunks)
// var: faithful per-class sequential recurrence, computed redundantly per R block.
//
// Round-5 sync redesign: round-4's __threadfence() (agent fence => buffer_wbl2/
// buffer_inv = full per-XCD L2 walks, executed by EVERY wave) caused a ~130us
// fence storm (VALUBusy 3.2%). Replaced by FLAGGED memory ops: partials are
// written/read with relaxed agent-scope atomics (sc0/sc1 write-through loads/
// stores -> coherent at the memory-side cache, no L2 maintenance), barrier spin
// is a relaxed agent LOAD (no RMW hammering). Zero cache-flush instructions.

__device__ __forceinline__ void agent_store_f(float* p, float v) {
    __hip_atomic_store(p, v, __ATOMIC_RELAXED, __HIP_MEMORY_SCOPE_AGENT);
}
__device__ __forceinline__ float agent_load_f(const float* p) {
    return __hip_atomic_load(p, __ATOMIC_RELAXED, __HIP_MEMORY_SCOPE_AGENT);
}

__device__ __forceinline__ void gemm_inner(const float (*As)[LSTR], const float (*Bs)[LSTR],
                                           int tx, int ty, float4* acc) {
#pragma unroll
    for (int kk = 0; kk < 32; ++kk) {
        const float4 a = *(const float4*)&As[kk][ty * 4];
        const float4 b = *(const float4*)&Bs[kk][tx * 4];
        acc[0].x += a.x * b.x; acc[0].y += a.x * b.y; acc[0].z += a.x * b.z; acc[0].w += a.x * b.w;
        acc[1].x += a.y * b.x; acc[1].y += a.y * b.y; acc[1].z += a.y * b.z; acc[1].w += a.y * b.w;
        acc[2].x += a.z * b.x; acc[2].y += a.z * b.y; acc[2].z += a.z * b.z; acc[2].w += a.z * b.w;
        acc[3].x += a.w * b.x; acc[3].y += a.w * b.y; acc[3].z += a.w * b.z; acc[3].w += a.w * b.w;
    }
}

// grid: NBLK blocks x 256 threads.
//  bid <  256      : s1 partial. z=bid&3 (K chunk of 128), tile=bid>>2: bm=tile&15, bn=tile>>4.
//  256 <= bid < 384: R partial.  r=bid-256; z=r&7 (dim chunk of 64), tile=r>>3: bm=tile&3, bn=tile>>2.
//  bid >= 384      : no phase-1 work (barrier + phase-2 only).
__global__ __launch_bounds__(256) void fused_all(const float* __restrict__ df,
                                                 const int* __restrict__ gt,
                                                 const float* __restrict__ fc,
                                                 float* __restrict__ s1p,
                                                 float* __restrict__ Rp,
                                                 unsigned int* __restrict__ bar,
                                                 float* __restrict__ out) {
    __shared__ float As[32][LSTR];
    __shared__ float Bs[32][LSTR];
    __shared__ int gts[BSZ];
    __shared__ unsigned long long bmap[64 * 16];

    const int tid = threadIdx.x;
    const int bid = blockIdx.x;
    const int tx = tid & 15, ty = tid >> 4;

    float4 acc[4];
    acc[0] = make_float4(0.f, 0.f, 0.f, 0.f);
    acc[1] = acc[0]; acc[2] = acc[0]; acc[3] = acc[0];

    if (bid < 256) {
        // ------------------------------- s1 path -------------------------------
        const int z = bid & 3;
        const int tile = bid >> 2;
        const int bm = tile & 15, bn = tile >> 4;
        const int arow = tid >> 2;              // 0..63
        const int kq = (tid & 3) << 3;          // 0,8,16,24
        const float* Ag = df + (bm * 64 + arow) * NDF + z * 128 + kq;
        const float* Bg = fc + (bn * 64 + arow) * NDF + z * 128 + kq;

        float4 a0 = *(const float4*)Ag, a1 = *(const float4*)(Ag + 4);
        float4 b0 = *(const float4*)Bg, b1 = *(const float4*)(Bg + 4);
#pragma unroll 1
        for (int ks = 0; ks < 4; ++ks) {
            __syncthreads();
            As[kq + 0][arow] = a0.x; As[kq + 1][arow] = a0.y; As[kq + 2][arow] = a0.z; As[kq + 3][arow] = a0.w;
            As[kq + 4][arow] = a1.x; As[kq + 5][arow] = a1.y; As[kq + 6][arow] = a1.z; As[kq + 7][arow] = a1.w;
            Bs[kq + 0][arow] = b0.x; Bs[kq + 1][arow] = b0.y; Bs[kq + 2][arow] = b0.z; Bs[kq + 3][arow] = b0.w;
            Bs[kq + 4][arow] = b1.x; Bs[kq + 5][arow] = b1.y; Bs[kq + 6][arow] = b1.z; Bs[kq + 7][arow] = b1.w;
            __syncthreads();
            if (ks < 3) {
                const int off = (ks + 1) * 32;
                a0 = *(const float4*)(Ag + off); a1 = *(const float4*)(Ag + off + 4);
                b0 = *(const float4*)(Bg + off); b1 = *(const float4*)(Bg + off + 4);
            }
            gemm_inner(As, Bs, tx, ty, acc);
        }
        float* Cp = s1p + z * (BSZ * NCLS) + (bm * 64 + ty * 4) * NCLS + bn * 64 + tx * 4;
#pragma unroll
        for (int i = 0; i < 4; ++i) {
            agent_store_f(Cp + i * NCLS + 0, acc[i].x);
            agent_store_f(Cp + i * NCLS + 1, acc[i].y);
            agent_store_f(Cp + i * NCLS + 2, acc[i].z);
            agent_store_f(Cp + i * NCLS + 3, acc[i].w);
        }
    } else if (bid < 384) {
        // ------------------------------- R path --------------------------------
        const int r = bid - 256;
        const int z = r & 7;                    // dim chunk
        const int tile = r >> 3;
        const int bm = tile & 3, bn = tile >> 2;
        const int D0 = z * 64;
        const int clocal = tid >> 2;            // 0..63: class within tile
        const int dg = tid & 3;                 // 0..3: 16-dim group
        const int myclass = bm * 64 + clocal;
        const int dim0 = D0 + dg * 16;

        for (int i = tid; i < BSZ; i += 256) gts[i] = gt[i];
        for (int i = tid; i < 1024; i += 256) bmap[i] = 0ull;
        __syncthreads();
        // order-preserving per-class sample bitmap (64 classes x 1024 bits)
        for (int i = tid; i < BSZ; i += 256) {
            const int c = gts[i] - bm * 64;
            if ((unsigned)c < 64u) atomicOr(&bmap[c * 16 + (i >> 6)], 1ull << (i & 63));
        }
        const float* fct = fc + myclass * NDF + dim0;
        float fcq[16];
        {
            const float4 q0 = ((const float4*)fct)[0], q1 = ((const float4*)fct)[1];
            const float4 q2 = ((const float4*)fct)[2], q3 = ((const float4*)fct)[3];
            fcq[0]=q0.x; fcq[1]=q0.y; fcq[2]=q0.z; fcq[3]=q0.w;
            fcq[4]=q1.x; fcq[5]=q1.y; fcq[6]=q1.z; fcq[7]=q1.w;
            fcq[8]=q2.x; fcq[9]=q2.y; fcq[10]=q2.z; fcq[11]=q2.w;
            fcq[12]=q3.x; fcq[13]=q3.y; fcq[14]=q3.z; fcq[15]=q3.w;
        }
        __syncthreads();

        // sequential running-var recurrence for (myclass, dims dim0..dim0+16)
        float m[16], v[16];
#pragma unroll
        for (int j = 0; j < 16; ++j) { m[j] = 0.f; v[j] = 0.f; }
        float nf = 0.f;
        {
            int w = 0;
            unsigned long long bits = bmap[clocal * 16];
            auto next = [&]() -> int {
                while (bits == 0ull) {
                    if (w >= 15) return -1;
                    bits = bmap[clocal * 16 + (++w)];
                }
                const int b = __ffsll((unsigned long long)bits) - 1;
                bits &= bits - 1ull;
                return (w << 6) + b;
            };
            int cur = next();
            float f[16];
            if (cur >= 0) {
                const float* p = df + cur * NDF + dim0;
                const float4 q0 = ((const float4*)p)[0], q1 = ((const float4*)p)[1];
                const float4 q2 = ((const float4*)p)[2], q3 = ((const float4*)p)[3];
                f[0]=q0.x; f[1]=q0.y; f[2]=q0.z; f[3]=q0.w;
                f[4]=q1.x; f[5]=q1.y; f[6]=q1.z; f[7]=q1.w;
                f[8]=q2.x; f[9]=q2.y; f[10]=q2.z; f[11]=q2.w;
                f[12]=q3.x; f[13]=q3.y; f[14]=q3.z; f[15]=q3.w;
            }
            while (cur >= 0) {
                const int nxt = next();
                float g[16];
                if (nxt >= 0) {   // prefetch next sample before the dependent update
                    const float* p = df + nxt * NDF + dim0;
                    const float4 q0 = ((const float4*)p)[0], q1 = ((const float4*)p)[1];
                    const float4 q2 = ((const float4*)p)[2], q3 = ((const float4*)p)[3];
                    g[0]=q0.x; g[1]=q0.y; g[2]=q0.z; g[3]=q0.w;
                    g[4]=q1.x; g[5]=q1.y; g[6]=q1.z; g[7]=q1.w;
                    g[8]=q2.x; g[9]=q2.y; g[10]=q2.z; g[11]=q2.w;
                    g[12]=q3.x; g[13]=q3.y; g[14]=q3.z; g[15]=q3.w;
                }
                const float c2 = 1.0f / (nf + 1.0f);
                const float c1 = nf * c2;
                const float c12 = c1 * c2;
#pragma unroll
                for (int j = 0; j < 16; ++j) {
                    m[j] = m[j] * c1 + f[j] * c2;     // == f when nf==0
                    const float a = f[j] - m[j];
                    v[j] = v[j] * c1 + a * a * c12;
                }
                nf += 1.0f;
#pragma unroll
                for (int j = 0; j < 16; ++j) f[j] = g[j];
                cur = nxt;
            }
        }

        // GEMM: 4 k-steps over the 64-dim chunk (2 linear + 2 quadratic)
        const int crow = tid >> 2, kq = (tid & 3) << 3;
        const float* Bg = fc + (bn * 64 + crow) * NDF + D0;
        float4 b0 = *(const float4*)(Bg + kq), b1 = *(const float4*)(Bg + kq + 4);
#pragma unroll 1
        for (int ks = 0; ks < 4; ++ks) {
            const bool quad = (ks >= 2);
            float4 w0 = b0, w1 = b1;
            if (quad) {
                w0.x *= w0.x; w0.y *= w0.y; w0.z *= w0.z; w0.w *= w0.w;
                w1.x *= w1.x; w1.y *= w1.y; w1.z *= w1.z; w1.w *= w1.w;
            }
            __syncthreads();
            if ((dg >> 1) == (ks & 1)) {   // this thread's dims fall in this k-step
                const int kb = (dg & 1) * 16;
#pragma unroll
                for (int j = 0; j < 16; ++j) {
                    As[kb + j][clocal] = quad ? v[j] : (-2.f * fcq[j] * v[j]);
                }
            }
            Bs[kq + 0][crow] = w0.x; Bs[kq + 1][crow] = w0.y; Bs[kq + 2][crow] = w0.z; Bs[kq + 3][crow] = w0.w;
            Bs[kq + 4][crow] = w1.x; Bs[kq + 5][crow] = w1.y; Bs[kq + 6][crow] = w1.z; Bs[kq + 7][crow] = w1.w;
            __syncthreads();
            if (ks < 3) {   // prefetch next step's B columns (alternate 32-dim halves)
                const int off = ((ks + 1) & 1) * 32;
                b0 = *(const float4*)(Bg + off + kq);
                b1 = *(const float4*)(Bg + off + kq + 4);
            }
            gemm_inner(As, Bs, tx, ty, acc);
        }
        float* Cp = Rp + z * (NCLS * NCLS) + (bm * 64 + ty * 4) * NCLS + bn * 64 + tx * 4;
#pragma unroll
        for (int i = 0; i < 4; ++i) {
            agent_store_f(Cp + i * NCLS + 0, acc[i].x);
            agent_store_f(Cp + i * NCLS + 1, acc[i].y);
            agent_store_f(Cp + i * NCLS + 2, acc[i].z);
            agent_store_f(Cp + i * NCLS + 3, acc[i].w);
        }
    }
    // else: barrier-helper block, goes straight to the barrier.

    // ----------------------- device-scope grid barrier ------------------------
    // No fences: partials were written with sc-flagged write-through stores; the
    // compiler's s_waitcnt vmcnt(0) before s_barrier drains them to the coherence
    // point before the (agent-scope) arrival add. Spin uses relaxed agent LOADS.
    __syncthreads();
    if (tid == 0) {
        __hip_atomic_fetch_add(bar, 1u, __ATOMIC_RELAXED, __HIP_MEMORY_SCOPE_AGENT);
        while (__hip_atomic_load(bar, __ATOMIC_RELAXED, __HIP_MEMORY_SCOPE_AGENT) < (unsigned)NBLK)
            __builtin_amdgcn_s_sleep(2);
    }
    __syncthreads();

    // ------------------------------- phase 2 ----------------------------------
    // out[b,c] = (v1[b,c]-v1[b,t]) + 0.5*ALP*(vR[t,c]-vR[t,t]); 2 rows per block.
    // All partial reads are sc-flagged (bypass possibly-stale local L2).
    const int c = tid;
#pragma unroll 1
    for (int b = bid; b < BSZ; b += NBLK) {
        const int t = gt[b];   // input: read-only, safe to cache
        float v1 = 0.f, v1t = 0.f;
#pragma unroll
        for (int zz = 0; zz < 4; ++zz) {
            const float* row = s1p + zz * (BSZ * NCLS) + b * NCLS;
            v1 += agent_load_f(row + c);
            v1t += agent_load_f(row + t);    // same-address broadcast across the wave
        }
        float vR = 0.f, vRt = 0.f;
#pragma unroll
        for (int zz = 0; zz < 8; ++zz) {
            const float* row = Rp + zz * (NCLS * NCLS) + t * NCLS;
            vR += agent_load_f(row + c);
            vRt += agent_load_f(row + t);
        }
        out[b * NCLS + c] = (v1 - v1t) + 0.5f * ALP * (vR - vRt);
    }
}

// ---------------------------------------------------------------------------
extern "C" void kernel_launch(void* const* d_in, const int* in_sizes, int n_in,
                              void* d_out, int out_size, void* d_ws, size_t ws_size,
                              hipStream_t stream) {
    const float* df = (const float*)d_in[0];
    const int* gt = (const int*)d_in[1];
    const float* fc = (const float*)d_in[2];
    float* out = (float*)d_out;

    float* ws = (float*)d_ws;
    float* s1p = ws;                           // 4*BSZ*NCLS  = 1,048,576 f (4 MB)
    float* Rp = s1p + 4 * BSZ * NCLS;          // 8*NCLS*NCLS =   524,288 f (2 MB)
    unsigned int* bar = (unsigned int*)(Rp + 8 * NCLS * NCLS);

    hipMemsetAsync(bar, 0, sizeof(unsigned int), stream);  // reset barrier each call
    fused_all<<<NBLK, 256, 0, stream>>>(df, gt, fc, s1p, Rp, bar, out);
}

// Round 6
// 25.097 us; speedup vs baseline: 5.5031x; 2.4433x over previous
//
#include <hip/hip_runtime.h>

#define NCLS 256
#define NDF  512
#define BSZ  1024
#define ALP  0.1f

// score[b,c] = s1[b,c]-s1[b,t] + 0.5*ALP*(R[t,c]-R[t,t]),  t=gt[b]
//   s1 = df @ fc^T                        (1024x256x512, splitK=4, bf16 MFMA)
//   R[t,c] = sum_d (fc[c,d]^2 - 2 fc[c,d] fc[t,d]) var[t,d]
//            (256x256, 8 dim-chunks of 64, virtual K=128/block, bf16 MFMA)
//   var: faithful per-class sequential recurrence, redundant per R block.
// Two dispatches (kernel boundary = the cheap cross-XCD fence; round-4/5 showed
// in-kernel grid barriers cost 25-115us here via L2 maintenance / uncached traffic).
// MFMA per guide §3/§5 (m89/m97-verified): A/B frag lane l = T[l&15][(l>>4)*8+j],
// C/D: col=lane&15, row=(lane>>4)*4+reg. LDS rows 128B bf16, byte^=((row&7)<<4).

typedef __attribute__((ext_vector_type(8))) short bf16x8;
typedef __attribute__((ext_vector_type(4))) float f32x4;

// pack two fp32 -> one dword of two bf16 (RNE)
__device__ __forceinline__ unsigned rne_pk(float lo, float hi) {
    union { float f; unsigned u; } a, b;
    a.f = lo; b.f = hi;
    unsigned ua = (a.u + 0x7FFFu + ((a.u >> 16) & 1u)) >> 16;
    unsigned ub = (b.u + 0x7FFFu + ((b.u >> 16) & 1u)) & 0xFFFF0000u;
    return ua | ub;
}
// pack 8 fp32 (two float4) -> uint4 of 8 bf16
__device__ __forceinline__ uint4 pk16(float4 p, float4 q) {
    uint4 r;
    r.x = rne_pk(p.x, p.y); r.y = rne_pk(p.z, p.w);
    r.z = rne_pk(q.x, q.y); r.w = rne_pk(q.z, q.w);
    return r;
}

// grid: 384 blocks x 256 threads.
//  bid <  256: s1 partial. z=bid&3 (K chunk 128), tile=bid>>2: bm=tile&15, bn=tile>>4.
//  bid >= 256: R partial.  r=bid-256; z=r&7 (64-dim chunk), tile=r>>3: bm=tile&3, bn=tile>>2.
__global__ __launch_bounds__(256) void fused_main(const float* __restrict__ df,
                                                  const int* __restrict__ gt,
                                                  const float* __restrict__ fc,
                                                  float* __restrict__ s1p,
                                                  float* __restrict__ Rp) {
    __shared__ alignas(16) char Asb[64 * 128];   // 64 rows x 64 bf16 (128 B), swizzled
    __shared__ alignas(16) char Bsb[64 * 128];
    __shared__ int gts[BSZ];                     // R path only
    __shared__ unsigned long long bmap[64 * 16]; // R path only

    const int tid = threadIdx.x;
    const int bid = blockIdx.x;
    const int lane = tid & 63;
    const int wv = tid >> 6;                 // wave 0..3 -> 32x32 output quadrant
    const int wm = (wv >> 1) * 32, wn = (wv & 1) * 32;
    const int fr = lane & 15;                // frag row/col
    const int fkb = (lane >> 4) * 16;        // frag k byte offset (8 bf16)
    const int fswz = (fr & 7) << 4;          // row&7 == fr&7 (wm/mi offsets are x16)

    // staging mapping (both tiles, both paths): row sr, 16 floats at (tid&3)*16
    const int sr = tid >> 2;
    const int skb = (tid & 3) * 32;          // byte offset of 16 bf16
    const int sswz = (sr & 7) << 4;
    char* arow = Asb + sr * 128;
    char* brow = Bsb + sr * 128;

    f32x4 acc[2][2];
    acc[0][0] = 0.f; acc[0][1] = 0.f; acc[1][0] = 0.f; acc[1][1] = 0.f;

    auto mma_step = [&](int k0b) {           // one 32-k MFMA step (k0b in bytes: 0 or 64)
        const int kb = (k0b + fkb) ^ fswz;
        const bf16x8 aF0 = *(const bf16x8*)(Asb + (wm + fr) * 128 + kb);
        const bf16x8 aF1 = *(const bf16x8*)(Asb + (wm + 16 + fr) * 128 + kb);
        const bf16x8 bF0 = *(const bf16x8*)(Bsb + (wn + fr) * 128 + kb);
        const bf16x8 bF1 = *(const bf16x8*)(Bsb + (wn + 16 + fr) * 128 + kb);
        acc[0][0] = __builtin_amdgcn_mfma_f32_16x16x32_bf16(aF0, bF0, acc[0][0], 0, 0, 0);
        acc[0][1] = __builtin_amdgcn_mfma_f32_16x16x32_bf16(aF0, bF1, acc[0][1], 0, 0, 0);
        acc[1][0] = __builtin_amdgcn_mfma_f32_16x16x32_bf16(aF1, bF0, acc[1][0], 0, 0, 0);
        acc[1][1] = __builtin_amdgcn_mfma_f32_16x16x32_bf16(aF1, bF1, acc[1][1], 0, 0, 0);
    };
    auto store_tile = [&](float* base) {     // base = tile origin, stride NCLS
#pragma unroll
        for (int mi = 0; mi < 2; ++mi)
#pragma unroll
            for (int ni = 0; ni < 2; ++ni)
#pragma unroll
                for (int r2 = 0; r2 < 4; ++r2)
                    base[(wm + mi * 16 + (lane >> 4) * 4 + r2) * NCLS + wn + ni * 16 + fr] =
                        acc[mi][ni][r2];
    };

    if (bid < 256) {
        // ------------------------------- s1 path -------------------------------
        const int z = bid & 3;
        const int tile = bid >> 2;
        const int bm = tile & 15, bn = tile >> 4;
        const float* Ag = df + (bm * 64 + sr) * NDF + z * 128 + (tid & 3) * 16;
        const float* Bg = fc + (bn * 64 + sr) * NDF + z * 128 + (tid & 3) * 16;

        // ks0: k [0,64)
        float4 a0 = ((const float4*)Ag)[0], a1 = ((const float4*)Ag)[1],
               a2 = ((const float4*)Ag)[2], a3 = ((const float4*)Ag)[3];
        float4 b0 = ((const float4*)Bg)[0], b1 = ((const float4*)Bg)[1],
               b2 = ((const float4*)Bg)[2], b3 = ((const float4*)Bg)[3];
        *(uint4*)(arow + (skb ^ sswz)) = pk16(a0, a1);
        *(uint4*)(arow + ((skb + 16) ^ sswz)) = pk16(a2, a3);
        *(uint4*)(brow + (skb ^ sswz)) = pk16(b0, b1);
        *(uint4*)(brow + ((skb + 16) ^ sswz)) = pk16(b2, b3);
        __syncthreads();
        // prefetch ks1: k [64,128)
        a0 = ((const float4*)(Ag + 64))[0]; a1 = ((const float4*)(Ag + 64))[1];
        a2 = ((const float4*)(Ag + 64))[2]; a3 = ((const float4*)(Ag + 64))[3];
        b0 = ((const float4*)(Bg + 64))[0]; b1 = ((const float4*)(Bg + 64))[1];
        b2 = ((const float4*)(Bg + 64))[2]; b3 = ((const float4*)(Bg + 64))[3];
        mma_step(0); mma_step(64);
        __syncthreads();
        *(uint4*)(arow + (skb ^ sswz)) = pk16(a0, a1);
        *(uint4*)(arow + ((skb + 16) ^ sswz)) = pk16(a2, a3);
        *(uint4*)(brow + (skb ^ sswz)) = pk16(b0, b1);
        *(uint4*)(brow + ((skb + 16) ^ sswz)) = pk16(b2, b3);
        __syncthreads();
        mma_step(0); mma_step(64);
        store_tile(s1p + z * (BSZ * NCLS) + (bm * 64) * NCLS + bn * 64);
    } else {
        // ------------------------------- R path --------------------------------
        const int r = bid - 256;
        const int z = r & 7;
        const int tile = r >> 3;
        const int bm = tile & 3, bn = tile >> 2;
        const int D0 = z * 64;
        const int clocal = sr;                  // class within tile (== staging row)
        const int dg = tid & 3;                 // 16-dim group
        const int myclass = bm * 64 + clocal;
        const int dim0 = D0 + dg * 16;

        // B tile global loads (independent -> issue first)
        const float* Bg = fc + (bn * 64 + sr) * NDF + D0 + (tid & 3) * 16;
        const float4 b0 = ((const float4*)Bg)[0], b1 = ((const float4*)Bg)[1],
                     b2 = ((const float4*)Bg)[2], b3 = ((const float4*)Bg)[3];

        for (int i = tid; i < BSZ; i += 256) gts[i] = gt[i];
        for (int i = tid; i < 1024; i += 256) bmap[i] = 0ull;
        __syncthreads();
        // order-preserving per-class sample bitmap (64 classes x 1024 bits)
        for (int i = tid; i < BSZ; i += 256) {
            const int c = gts[i] - bm * 64;
            if ((unsigned)c < 64u) atomicOr(&bmap[c * 16 + (i >> 6)], 1ull << (i & 63));
        }
        const float* fct = fc + myclass * NDF + dim0;
        float fcq[16];
        {
            const float4 q0 = ((const float4*)fct)[0], q1 = ((const float4*)fct)[1];
            const float4 q2 = ((const float4*)fct)[2], q3 = ((const float4*)fct)[3];
            fcq[0]=q0.x; fcq[1]=q0.y; fcq[2]=q0.z; fcq[3]=q0.w;
            fcq[4]=q1.x; fcq[5]=q1.y; fcq[6]=q1.z; fcq[7]=q1.w;
            fcq[8]=q2.x; fcq[9]=q2.y; fcq[10]=q2.z; fcq[11]=q2.w;
            fcq[12]=q3.x; fcq[13]=q3.y; fcq[14]=q3.z; fcq[15]=q3.w;
        }
        __syncthreads();

        // sequential running-var recurrence for (myclass, dims dim0..dim0+16)
        float m[16], v[16];
#pragma unroll
        for (int j = 0; j < 16; ++j) { m[j] = 0.f; v[j] = 0.f; }
        float nf = 0.f;
        {
            int w = 0;
            unsigned long long bits = bmap[clocal * 16];
            auto next = [&]() -> int {
                while (bits == 0ull) {
                    if (w >= 15) return -1;
                    bits = bmap[clocal * 16 + (++w)];
                }
                const int b = __ffsll((unsigned long long)bits) - 1;
                bits &= bits - 1ull;
                return (w << 6) + b;
            };
            int cur = next();
            float f[16];
            if (cur >= 0) {
                const float* p = df + cur * NDF + dim0;
                const float4 q0 = ((const float4*)p)[0], q1 = ((const float4*)p)[1];
                const float4 q2 = ((const float4*)p)[2], q3 = ((const float4*)p)[3];
                f[0]=q0.x; f[1]=q0.y; f[2]=q0.z; f[3]=q0.w;
                f[4]=q1.x; f[5]=q1.y; f[6]=q1.z; f[7]=q1.w;
                f[8]=q2.x; f[9]=q2.y; f[10]=q2.z; f[11]=q2.w;
                f[12]=q3.x; f[13]=q3.y; f[14]=q3.z; f[15]=q3.w;
            }
            while (cur >= 0) {
                const int nxt = next();
                float g[16];
                if (nxt >= 0) {   // prefetch next sample before the dependent update
                    const float* p = df + nxt * NDF + dim0;
                    const float4 q0 = ((const float4*)p)[0], q1 = ((const float4*)p)[1];
                    const float4 q2 = ((const float4*)p)[2], q3 = ((const float4*)p)[3];
                    g[0]=q0.x; g[1]=q0.y; g[2]=q0.z; g[3]=q0.w;
                    g[4]=q1.x; g[5]=q1.y; g[6]=q1.z; g[7]=q1.w;
                    g[8]=q2.x; g[9]=q2.y; g[10]=q2.z; g[11]=q2.w;
                    g[12]=q3.x; g[13]=q3.y; g[14]=q3.z; g[15]=q3.w;
                }
                const float c2 = 1.0f / (nf + 1.0f);
                const float c1 = nf * c2;
                const float c12 = c1 * c2;
#pragma unroll
                for (int j = 0; j < 16; ++j) {
                    m[j] = m[j] * c1 + f[j] * c2;     // == f when nf==0
                    const float a = f[j] - m[j];
                    v[j] = v[j] * c1 + a * a * c12;
                }
                nf += 1.0f;
#pragma unroll
                for (int j = 0; j < 16; ++j) f[j] = g[j];
                cur = nxt;
            }
        }

        // virtual ks0 (linear): A = -2*fc_t*var (from regs), B = fc
        {
            float4 p0, p1, p2, p3;
            p0.x=-2.f*fcq[0]*v[0];  p0.y=-2.f*fcq[1]*v[1];  p0.z=-2.f*fcq[2]*v[2];  p0.w=-2.f*fcq[3]*v[3];
            p1.x=-2.f*fcq[4]*v[4];  p1.y=-2.f*fcq[5]*v[5];  p1.z=-2.f*fcq[6]*v[6];  p1.w=-2.f*fcq[7]*v[7];
            p2.x=-2.f*fcq[8]*v[8];  p2.y=-2.f*fcq[9]*v[9];  p2.z=-2.f*fcq[10]*v[10]; p2.w=-2.f*fcq[11]*v[11];
            p3.x=-2.f*fcq[12]*v[12]; p3.y=-2.f*fcq[13]*v[13]; p3.z=-2.f*fcq[14]*v[14]; p3.w=-2.f*fcq[15]*v[15];
            *(uint4*)(arow + (skb ^ sswz)) = pk16(p0, p1);
            *(uint4*)(arow + ((skb + 16) ^ sswz)) = pk16(p2, p3);
            *(uint4*)(brow + (skb ^ sswz)) = pk16(b0, b1);
            *(uint4*)(brow + ((skb + 16) ^ sswz)) = pk16(b2, b3);
        }
        __syncthreads();
        mma_step(0); mma_step(64);
        __syncthreads();
        // virtual ks1 (quadratic): A = var, B = fc^2
        {
            float4 p0, p1, p2, p3, s0, s1, s2, s3;
            p0.x=v[0];  p0.y=v[1];  p0.z=v[2];  p0.w=v[3];
            p1.x=v[4];  p1.y=v[5];  p1.z=v[6];  p1.w=v[7];
            p2.x=v[8];  p2.y=v[9];  p2.z=v[10]; p2.w=v[11];
            p3.x=v[12]; p3.y=v[13]; p3.z=v[14]; p3.w=v[15];
            s0.x=b0.x*b0.x; s0.y=b0.y*b0.y; s0.z=b0.z*b0.z; s0.w=b0.w*b0.w;
            s1.x=b1.x*b1.x; s1.y=b1.y*b1.y; s1.z=b1.z*b1.z; s1.w=b1.w*b1.w;
            s2.x=b2.x*b2.x; s2.y=b2.y*b2.y; s2.z=b2.z*b2.z; s2.w=b2.w*b2.w;
            s3.x=b3.x*b3.x; s3.y=b3.y*b3.y; s3.z=b3.z*b3.z; s3.w=b3.w*b3.w;
            *(uint4*)(arow + (skb ^ sswz)) = pk16(p0, p1);
            *(uint4*)(arow + ((skb + 16) ^ sswz)) = pk16(p2, p3);
            *(uint4*)(brow + (skb ^ sswz)) = pk16(s0, s1);
            *(uint4*)(brow + ((skb + 16) ^ sswz)) = pk16(s2, s3);
        }
        __syncthreads();
        mma_step(0); mma_step(64);
        store_tile(Rp + z * (NCLS * NCLS) + (bm * 64) * NCLS + bn * 64);
    }
}

// ---------------------------------------------------------------------------
// Epilogue: fold 4 s1 + 8 R partials; out[b,c]=(v1-v1[t]) + 0.05*(vR-vR[t]).
// 256 blocks x 256 thr: wave w handles row b=bid*4+w (wave-uniform t), float4 cols.
__global__ __launch_bounds__(256) void epilogue_kernel(const float* __restrict__ s1p,
                                                       const float* __restrict__ Rp,
                                                       const int* __restrict__ gt,
                                                       float* __restrict__ out) {
    const int b = blockIdx.x * 4 + (threadIdx.x >> 6);
    const int cq = (threadIdx.x & 63) * 4;
    const int t = gt[b];
    float4 v1 = make_float4(0.f, 0.f, 0.f, 0.f);
    float v1t = 0.f;
#pragma unroll
    for (int zz = 0; zz < 4; ++zz) {
        const float* row = s1p + zz * (BSZ * NCLS) + b * NCLS;
        const float4 q = *(const float4*)(row + cq);
        v1.x += q.x; v1.y += q.y; v1.z += q.z; v1.w += q.w;
        v1t += row[t];
    }
    float4 vR = make_float4(0.f, 0.f, 0.f, 0.f);
    float vRt = 0.f;
#pragma unroll
    for (int zz = 0; zz < 8; ++zz) {
        const float* row = Rp + zz * (NCLS * NCLS) + t * NCLS;
        const float4 q = *(const float4*)(row + cq);
        vR.x += q.x; vR.y += q.y; vR.z += q.z; vR.w += q.w;
        vRt += row[t];
    }
    float4 o;
    o.x = (v1.x - v1t) + 0.5f * ALP * (vR.x - vRt);
    o.y = (v1.y - v1t) + 0.5f * ALP * (vR.y - vRt);
    o.z = (v1.z - v1t) + 0.5f * ALP * (vR.z - vRt);
    o.w = (v1.w - v1t) + 0.5f * ALP * (vR.w - vRt);
    *(float4*)(out + b * NCLS + cq) = o;
}

// ---------------------------------------------------------------------------
extern "C" void kernel_launch(void* const* d_in, const int* in_sizes, int n_in,
                              void* d_out, int out_size, void* d_ws, size_t ws_size,
                              hipStream_t stream) {
    const float* df = (const float*)d_in[0];
    const int* gt = (const int*)d_in[1];
    const float* fc = (const float*)d_in[2];
    float* out = (float*)d_out;

    float* ws = (float*)d_ws;
    float* s1p = ws;                           // 4*BSZ*NCLS  = 1,048,576 f (4 MB)
    float* Rp = s1p + 4 * BSZ * NCLS;          // 8*NCLS*NCLS =   524,288 f (2 MB)

    fused_main<<<384, 256, 0, stream>>>(df, gt, fc, s1p, Rp);
    epilogue_kernel<<<256, 256, 0, stream>>>(s1p, Rp, gt, out);
}